// Round 1
// baseline (508.050 us; speedup 1.0000x reference)
//
#include <hip/hip_runtime.h>
#include <hip/hip_bf16.h>
#include <math.h>

// Problem constants (from reference)
#define NN 8192      // num nodes
#define DD 128       // in_dim
#define KK 4096      // k = max(2, int(0.5*N))
#define NW 256       // NN/32 words per full-row bitset
#define KW 128       // KK/32 words per selected-row bitset

// ---------------------------------------------------------------------------
// K1: scores[i] = sigmoid(h[i,:]·W + b), computed in double for a correctly-
// rounded fp32 result (best proxy for the reference's fp32 ordering).
// ---------------------------------------------------------------------------
__global__ void scores_kernel(const float* __restrict__ h,
                              const float* __restrict__ W,
                              const float* __restrict__ b,
                              float* __restrict__ scores) {
    __shared__ float w[DD];
    int tid = threadIdx.x;
    if (tid < DD) w[tid] = W[tid];
    __syncthreads();
    int i = blockIdx.x * blockDim.x + tid;
    if (i < NN) {
        const float* hr = h + i * DD;
        double x = 0.0;
        #pragma unroll 8
        for (int d = 0; d < DD; ++d) x += (double)hr[d] * (double)w[d];
        x += (double)b[0];
        double s = 1.0 / (1.0 + exp(-x));
        scores[i] = (float)s;
    }
}

// ---------------------------------------------------------------------------
// K2: exact stable top-k via rank-sort. rank(i) = #{j : v_j > v_i or
// (v_j == v_i and j < i)}  == position in (desc value, asc index) order.
// One block per element i; scores (32KB) stays hot in L1.
// ---------------------------------------------------------------------------
__global__ void rank_kernel(const float* __restrict__ scores,
                            int* __restrict__ idxs,
                            float* __restrict__ vals) {
    int i = blockIdx.x;
    int tid = threadIdx.x;
    float vi = scores[i];
    int cnt = 0;
    #pragma unroll 4
    for (int j = tid; j < NN; j += 256) {
        float vj = scores[j];
        cnt += (vj > vi || (vj == vi && j < i)) ? 1 : 0;
    }
    __shared__ int red[256];
    red[tid] = cnt;
    __syncthreads();
    for (int s = 128; s > 0; s >>= 1) {
        if (tid < s) red[tid] += red[tid + s];
        __syncthreads();
    }
    if (tid == 0) {
        int r = red[0];
        if (r < KK) { idxs[r] = i; vals[r] = vi; }
    }
}

// ---------------------------------------------------------------------------
// K3: new_h[r,:] = h[idx[r],:] * vals[r]
// ---------------------------------------------------------------------------
__global__ void newh_kernel(const float* __restrict__ h,
                            const int* __restrict__ idxs,
                            const float* __restrict__ vals,
                            float* __restrict__ out_newh) {
    int t = blockIdx.x * 256 + threadIdx.x;   // over KK*DD
    int r = t >> 7;
    int d = t & 127;
    out_newh[t] = h[idxs[r] * DD + d] * vals[r];
}

// K3b: idx output as float
__global__ void idxout_kernel(const int* __restrict__ idxs,
                              float* __restrict__ out_idx) {
    int t = blockIdx.x * 256 + threadIdx.x;
    if (t < KK) out_idx[t] = (float)idxs[t];
}

// ---------------------------------------------------------------------------
// K4a: binarize g into row bitsets A_bits[l, w] via wave ballot.
// One thread per element, coalesced; one 8B store per 64 elements.
// ---------------------------------------------------------------------------
__global__ void bitize_kernel(const float* __restrict__ g,
                              unsigned long long* __restrict__ A_bits64) {
    long long t = (long long)blockIdx.x * 256 + threadIdx.x;  // over NN*NN
    float v = g[t];
    unsigned long long m = __ballot(v != 0.0f);
    if ((threadIdx.x & 63) == 0) {
        A_bits64[t >> 6] = m;
    }
}

// ---------------------------------------------------------------------------
// K4b: column-permuted bitset  A_perm[l, c-bit] = A[l, idx[c]].
// Block per row l; gather bits from LDS-resident row, assemble via ballot.
// ---------------------------------------------------------------------------
__global__ void perm_kernel(const unsigned int* __restrict__ A_bits,
                            const int* __restrict__ idxs,
                            unsigned int* __restrict__ A_perm) {
    __shared__ unsigned int srow[NW];
    int l = blockIdx.x;
    int tid = threadIdx.x;           // 128 threads = 2 waves
    int lane = tid & 63;
    for (int t = tid; t < NW; t += 128) srow[t] = A_bits[l * NW + t];
    __syncthreads();
    unsigned long long* out = (unsigned long long*)(A_perm + l * KW);
    for (int c = tid; c < KK; c += 128) {
        int id = idxs[c];            // L1-hot 16KB table, coalesced
        bool bit = (srow[id >> 5] >> (id & 31)) & 1u;
        unsigned long long m = __ballot(bit);
        if (lane == 0) out[c >> 6] = m;
    }
}

// ---------------------------------------------------------------------------
// K5: B_sub row r = OR over neighbors l of idx[r] of A_perm[l,:]
//     degrees[r] = popcount(row)  (== row-sum over selected columns)
// ---------------------------------------------------------------------------
__global__ void union_kernel(const unsigned int* __restrict__ A_bits,
                             const unsigned int* __restrict__ A_perm,
                             const int* __restrict__ idxs,
                             unsigned int* __restrict__ B_sub,
                             int* __restrict__ degs) {
    __shared__ unsigned int srow[NW];
    __shared__ int nbrs[512];
    __shared__ int ncnt;
    __shared__ int red[128];
    int r = blockIdx.x;
    int tid = threadIdx.x;          // 128 threads
    if (tid == 0) ncnt = 0;
    __syncthreads();
    int node = idxs[r];
    for (int t = tid; t < NW; t += 128) srow[t] = A_bits[node * NW + t];
    __syncthreads();
    for (int t = tid; t < NW; t += 128) {
        unsigned int word = srow[t];
        while (word) {
            int bpos = __ffs(word) - 1;
            word &= word - 1;
            int pos = atomicAdd(&ncnt, 1);
            if (pos < 512) nbrs[pos] = t * 32 + bpos;
        }
    }
    __syncthreads();
    int n = ncnt < 512 ? ncnt : 512;
    unsigned int acc = 0u;
    int w = tid;
    for (int q = 0; q < n; ++q) {
        int l = nbrs[q];
        acc |= A_perm[l * KW + w];   // 512B coalesced per iteration
    }
    B_sub[r * KW + w] = acc;
    red[tid] = __popc(acc);
    __syncthreads();
    for (int s = 64; s > 0; s >>= 1) {
        if (tid < s) red[tid] += red[tid + s];
        __syncthreads();
    }
    if (tid == 0) degs[r] = red[0];
}

// K5b: rdeg[c] = 1.0f / deg[c]  (IEEE fp32 divide, matches reference bitwise)
__global__ void rdeg_kernel(const int* __restrict__ degs,
                            float* __restrict__ rdeg) {
    int c = blockIdx.x * 256 + threadIdx.x;
    if (c < KK) rdeg[c] = 1.0f / (float)degs[c];
}

// ---------------------------------------------------------------------------
// K6: g_new[r,c] = B_sub[r] bit c ? rdeg[c] : 0   (float4 stores)
// ---------------------------------------------------------------------------
__global__ void writeg_kernel(const unsigned int* __restrict__ B_sub,
                              const float* __restrict__ rdeg,
                              float* __restrict__ g_new) {
    int r = blockIdx.y;
    int c4 = blockIdx.x * 256 + threadIdx.x;   // index of float4
    int c = c4 * 4;
    unsigned int word = B_sub[r * KW + (c >> 5)];
    float4 rv = ((const float4*)rdeg)[c4];
    int sh = c & 31;                           // multiple of 4, <= 28
    float4 o;
    o.x = ((word >> sh) & 1u) ? rv.x : 0.0f;
    o.y = ((word >> (sh + 1)) & 1u) ? rv.y : 0.0f;
    o.z = ((word >> (sh + 2)) & 1u) ? rv.z : 0.0f;
    o.w = ((word >> (sh + 3)) & 1u) ? rv.w : 0.0f;
    ((float4*)g_new)[(long long)r * (KK / 4) + c4] = o;
}

// ---------------------------------------------------------------------------
extern "C" void kernel_launch(void* const* d_in, const int* in_sizes, int n_in,
                              void* d_out, int out_size, void* d_ws, size_t ws_size,
                              hipStream_t stream) {
    const float* g = (const float*)d_in[0];   // [NN, NN]
    const float* h = (const float*)d_in[1];   // [NN, DD]
    const float* W = (const float*)d_in[2];   // [DD]
    const float* b = (const float*)d_in[3];   // [1]

    float* out = (float*)d_out;
    float* out_gnew = out;                          // KK*KK
    float* out_newh = out + (long long)KK * KK;     // KK*DD
    float* out_idx  = out_newh + KK * DD;           // KK

    // d_ws layout (~2.1 MB)
    char* ws = (char*)d_ws;
    float*        scores = (float*)(ws + 0);              // 32 KB
    int*          idxs   = (int*)(ws + 32768);            // 16 KB
    float*        vals   = (float*)(ws + 49152);          // 16 KB
    int*          degs   = (int*)(ws + 65536);            // 16 KB
    float*        rdeg   = (float*)(ws + 81920);          // 16 KB
    unsigned int* B_sub  = (unsigned int*)(ws + 98304);   // 2 MB

    // Big bitset scratch lives in the g_new output region (overwritten last):
    // A_bits: 8 MB at d_out+0, A_perm: 4 MB at d_out+8MB. g_new is 64 MB.
    unsigned int* A_bits = (unsigned int*)d_out;
    unsigned int* A_perm = (unsigned int*)d_out + (long long)NN * NW;

    // K4a first (largest read: all of g, 256 MB)
    bitize_kernel<<<(long long)NN * NN / 256, 256, 0, stream>>>(
        g, (unsigned long long*)A_bits);

    // K1: scores
    scores_kernel<<<NN / 256, 256, 0, stream>>>(h, W, b, scores);

    // K2: stable top-k rank sort
    rank_kernel<<<NN, 256, 0, stream>>>(scores, idxs, vals);

    // K3/K3b: new_h and idx outputs
    newh_kernel<<<KK * DD / 256, 256, 0, stream>>>(h, idxs, vals, out_newh);
    idxout_kernel<<<KK / 256, 256, 0, stream>>>(idxs, out_idx);

    // K4b: column-permuted bitsets
    perm_kernel<<<NN, 128, 0, stream>>>(A_bits, idxs, A_perm);

    // K5: row unions -> B_sub bits + degrees
    union_kernel<<<KK, 128, 0, stream>>>(A_bits, A_perm, idxs, B_sub, degs);

    // K5b: reciprocal degrees
    rdeg_kernel<<<KK / 256, 256, 0, stream>>>(degs, rdeg);

    // K6: expand to fp32 g_new (overwrites bitset scratch; it is dead now)
    dim3 wg_grid(KK / 4 / 256, KK);
    writeg_kernel<<<wg_grid, 256, 0, stream>>>(B_sub, rdeg, out_gnew);
}

// Round 2
// 448.799 us; speedup vs baseline: 1.1320x; 1.1320x over previous
//
#include <hip/hip_runtime.h>
#include <hip/hip_bf16.h>
#include <math.h>

// Problem constants (from reference)
#define NN 8192      // num nodes
#define DD 128       // in_dim
#define KK 4096      // k = max(2, int(0.5*N))
#define NW 256       // NN/32 words per full-row bitset
#define KW 128       // KK/32 words per selected-row bitset
#define MAXNBR 768   // binomial(8192,0.01): mean 82, sd 9 -> 768 is ~76 sd

// ---------------------------------------------------------------------------
// K1: scores[i] = sigmoid(h[i,:]·W + b), fp64 accumulate for a correctly-
// rounded fp32 score (proxy for the reference's fp32 ordering).
// ---------------------------------------------------------------------------
__global__ void scores_kernel(const float* __restrict__ h,
                              const float* __restrict__ W,
                              const float* __restrict__ b,
                              float* __restrict__ scores) {
    __shared__ float w[DD];
    int tid = threadIdx.x;
    if (tid < DD) w[tid] = W[tid];
    __syncthreads();
    int i = blockIdx.x * blockDim.x + tid;
    if (i < NN) {
        const float4* hr = (const float4*)(h + i * DD);
        double x = 0.0;
        #pragma unroll
        for (int q = 0; q < DD / 4; ++q) {
            float4 v = hr[q];
            x += (double)v.x * (double)w[4 * q];
            x += (double)v.y * (double)w[4 * q + 1];
            x += (double)v.z * (double)w[4 * q + 2];
            x += (double)v.w * (double)w[4 * q + 3];
        }
        x += (double)b[0];
        double s = 1.0 / (1.0 + exp(-x));
        scores[i] = (float)s;
    }
}

// ---------------------------------------------------------------------------
// K2: exact stable top-k via rank-sort. rank(i) = #{j : v_j > v_i or
// (v_j == v_i and j < i)}  == position in (desc value, asc index) order.
// Also emits the float idx output (fused former idxout_kernel).
// ---------------------------------------------------------------------------
__global__ void rank_kernel(const float* __restrict__ scores,
                            int* __restrict__ idxs,
                            float* __restrict__ vals,
                            float* __restrict__ out_idx) {
    int i = blockIdx.x;
    int tid = threadIdx.x;
    float vi = scores[i];
    int cnt = 0;
    #pragma unroll 4
    for (int j = tid; j < NN; j += 256) {
        float vj = scores[j];
        cnt += (vj > vi || (vj == vi && j < i)) ? 1 : 0;
    }
    __shared__ int red[256];
    red[tid] = cnt;
    __syncthreads();
    for (int s = 128; s > 0; s >>= 1) {
        if (tid < s) red[tid] += red[tid + s];
        __syncthreads();
    }
    if (tid == 0) {
        int r = red[0];
        if (r < KK) {
            idxs[r] = i;
            vals[r] = vi;
            out_idx[r] = (float)i;
        }
    }
}

// ---------------------------------------------------------------------------
// K3: new_h[r,:] = h[idx[r],:] * vals[r]   (float4 path)
// ---------------------------------------------------------------------------
__global__ void newh_kernel(const float* __restrict__ h,
                            const int* __restrict__ idxs,
                            const float* __restrict__ vals,
                            float* __restrict__ out_newh) {
    int t = blockIdx.x * 256 + threadIdx.x;   // over KK*DD/4
    int r = t >> 5;                           // DD/4 = 32 float4 per row
    int q = t & 31;
    float s = vals[r];
    float4 v = ((const float4*)(h + idxs[r] * DD))[q];
    float4 o = make_float4(v.x * s, v.y * s, v.z * s, v.w * s);
    ((float4*)out_newh)[t] = o;
}

// ---------------------------------------------------------------------------
// K4: binarize g into row bitsets. One 32-bit word per thread from 8 float4
// loads (128 B/thread, every fetched byte used, coalesced u32 store).
// ---------------------------------------------------------------------------
__global__ void bitize_kernel(const float4* __restrict__ g4,
                              unsigned int* __restrict__ A_bits) {
    long long t = (long long)blockIdx.x * 256 + threadIdx.x;  // word index, NN*NN/32 total
    const float4* p = g4 + t * 8;
    unsigned int u = 0;
    #pragma unroll
    for (int q = 0; q < 8; ++q) {
        float4 v = p[q];
        u |= (unsigned int)(v.x != 0.0f) << (4 * q);
        u |= (unsigned int)(v.y != 0.0f) << (4 * q + 1);
        u |= (unsigned int)(v.z != 0.0f) << (4 * q + 2);
        u |= (unsigned int)(v.w != 0.0f) << (4 * q + 3);
    }
    A_bits[t] = u;
}

// ---------------------------------------------------------------------------
// K5: for each selected row r: full 2-hop row = OR over neighbors l of
// idx[r] of A_bits[l,:] (1KB coalesced rows, L2-resident), then gather the
// selected columns (idx) -> B_perm bits + degree popcount -> rdeg[r].
// Fuses former perm_kernel + union_kernel + rdeg_kernel.
// ---------------------------------------------------------------------------
__global__ void union_kernel(const unsigned int* __restrict__ A_bits,
                             const int* __restrict__ idxs,
                             unsigned int* __restrict__ B_perm,
                             float* __restrict__ rdeg) {
    __shared__ unsigned int srow[NW];   // adjacency row of node idx[r]
    __shared__ unsigned int sOR[NW];    // OR-accumulated 2-hop row
    __shared__ int nbrs[MAXNBR];
    __shared__ int ncnt;
    __shared__ int red[128];
    int r = blockIdx.x;
    int tid = threadIdx.x;              // 128 threads = 2 waves
    if (tid == 0) ncnt = 0;
    __syncthreads();
    int node = idxs[r];
    for (int t = tid; t < NW; t += 128) srow[t] = A_bits[node * NW + t];
    __syncthreads();
    // extract neighbor list of idx[r]
    for (int t = tid; t < NW; t += 128) {
        unsigned int word = srow[t];
        while (word) {
            int bpos = __ffs(word) - 1;
            word &= word - 1;
            int pos = atomicAdd(&ncnt, 1);
            if (pos < MAXNBR) nbrs[pos] = t * 32 + bpos;
        }
    }
    __syncthreads();
    int n = ncnt < MAXNBR ? ncnt : MAXNBR;
    unsigned int a0 = 0u, a1 = 0u;      // each thread owns 2 of 256 words
    for (int q = 0; q < n; ++q) {
        const unsigned int* row = A_bits + (long long)nbrs[q] * NW;
        a0 |= row[tid];
        a1 |= row[tid + 128];
    }
    sOR[tid] = a0;
    sOR[tid + 128] = a1;
    __syncthreads();
    // gather selected columns: bit c of B_perm row r = sOR bit idx[c]
    int lane = tid & 63;
    int cnt = 0;
    unsigned long long* outB = (unsigned long long*)(B_perm + r * KW);
    for (int c = tid; c < KK; c += 128) {
        int id = idxs[c];               // L1-hot 16KB table, coalesced
        int bit = (sOR[id >> 5] >> (id & 31)) & 1;
        unsigned long long m = __ballot(bit != 0);
        if (lane == 0) outB[c >> 6] = m;
        cnt += bit;
    }
    red[tid] = cnt;
    __syncthreads();
    for (int s = 64; s > 0; s >>= 1) {
        if (tid < s) red[tid] += red[tid + s];
        __syncthreads();
    }
    if (tid == 0) rdeg[r] = 1.0f / (float)red[0];   // IEEE divide matches ref
}

// ---------------------------------------------------------------------------
// K6: g_new[r,c] = B_perm[r] bit c ? rdeg[c] : 0   (column-normalize, float4)
// ---------------------------------------------------------------------------
__global__ void writeg_kernel(const unsigned int* __restrict__ B_perm,
                              const float* __restrict__ rdeg,
                              float* __restrict__ g_new) {
    int r = blockIdx.y;
    int c4 = blockIdx.x * 256 + threadIdx.x;   // index of float4
    int c = c4 * 4;
    unsigned int word = B_perm[r * KW + (c >> 5)];
    float4 rv = ((const float4*)rdeg)[c4];
    int sh = c & 31;                           // multiple of 4, <= 28
    float4 o;
    o.x = ((word >> sh) & 1u) ? rv.x : 0.0f;
    o.y = ((word >> (sh + 1)) & 1u) ? rv.y : 0.0f;
    o.z = ((word >> (sh + 2)) & 1u) ? rv.z : 0.0f;
    o.w = ((word >> (sh + 3)) & 1u) ? rv.w : 0.0f;
    ((float4*)g_new)[(long long)r * (KK / 4) + c4] = o;
}

// ---------------------------------------------------------------------------
extern "C" void kernel_launch(void* const* d_in, const int* in_sizes, int n_in,
                              void* d_out, int out_size, void* d_ws, size_t ws_size,
                              hipStream_t stream) {
    const float* g = (const float*)d_in[0];   // [NN, NN]
    const float* h = (const float*)d_in[1];   // [NN, DD]
    const float* W = (const float*)d_in[2];   // [DD]
    const float* b = (const float*)d_in[3];   // [1]

    float* out = (float*)d_out;
    float* out_gnew = out;                          // KK*KK
    float* out_newh = out + (long long)KK * KK;     // KK*DD
    float* out_idx  = out_newh + KK * DD;           // KK

    // d_ws layout (~2.1 MB)
    char* ws = (char*)d_ws;
    float*        scores = (float*)(ws + 0);              // 32 KB
    int*          idxs   = (int*)(ws + 32768);            // 16 KB
    float*        vals   = (float*)(ws + 49152);          // 16 KB
    float*        rdeg   = (float*)(ws + 65536);          // 16 KB
    unsigned int* B_perm = (unsigned int*)(ws + 98304);   // 2 MB (512B-aligned)

    // A_bits (8 MB) lives in the g_new output region; dead before writeg runs.
    unsigned int* A_bits = (unsigned int*)d_out;

    // K4 first (largest read: all of g, 256 MB)
    bitize_kernel<<<(NN / 32) * (NN / 256), 256, 0, stream>>>(
        (const float4*)g, A_bits);

    // K1: scores
    scores_kernel<<<NN / 256, 256, 0, stream>>>(h, W, b, scores);

    // K2: stable top-k rank sort (+ float idx output)
    rank_kernel<<<NN, 256, 0, stream>>>(scores, idxs, vals, out_idx);

    // K3: new_h
    newh_kernel<<<KK * DD / 4 / 256, 256, 0, stream>>>(h, idxs, vals, out_newh);

    // K5: row unions -> permuted bits + reciprocal degrees
    union_kernel<<<KK, 128, 0, stream>>>(A_bits, idxs, B_perm, rdeg);

    // K6: expand to fp32 g_new (overwrites A_bits scratch; it is dead now)
    dim3 wg_grid(KK / 4 / 256, KK);
    writeg_kernel<<<wg_grid, 256, 0, stream>>>(B_perm, rdeg, out_gnew);
}

// Round 3
// 441.680 us; speedup vs baseline: 1.1503x; 1.0161x over previous
//
#include <hip/hip_runtime.h>
#include <hip/hip_bf16.h>
#include <math.h>

// Problem constants (from reference)
#define NN 8192      // num nodes
#define DD 128       // in_dim
#define KK 4096      // k = max(2, int(0.5*N))
#define NW 256       // NN/32 words per full-row bitset
#define KW 128       // KK/32 words per selected-row bitset
#define MAXNBR 768   // binomial(8192,0.01): mean 82, sd 9 -> huge margin
#define NBITBLK 8192 // bitize blocks: 8192 blk * 256 thr * 8 f4 = NN*NN/4 f4

typedef unsigned int u32;
typedef unsigned long long u64;

// spread 8 bits of x to bit positions 0,4,8,...,28
__device__ __forceinline__ u32 spread4(u32 x) {
    x = (x | (x << 12)) & 0x000F000Fu;
    x = (x | (x << 6))  & 0x03030303u;
    x = (x | (x << 3))  & 0x11111111u;
    return x;
}

// ---------------------------------------------------------------------------
// K1 (fused): blocks [0, NBITBLK): binarize g into row bitsets with textbook
// lane-contiguous float4 loads (1KB/wave-instr) + 4x ballot packing.
// Blocks [NBITBLK, NBITBLK+32): scores[i] = sigmoid(h[i,:]·W + b) in fp64.
// ---------------------------------------------------------------------------
__global__ void bitize_scores_kernel(const float4* __restrict__ g4,
                                     u32* __restrict__ A_bits,
                                     const float* __restrict__ h,
                                     const float* __restrict__ W,
                                     const float* __restrict__ b,
                                     float* __restrict__ scores) {
    __shared__ float w[DD];
    int tid = threadIdx.x;
    if (blockIdx.x < NBITBLK) {
        // ---- bitize ----
        int lane = tid & 63;
        long long f4base = (long long)blockIdx.x * 256 + (tid & ~63);
        const long long STRIDE = (long long)NBITBLK * 256;
        #pragma unroll
        for (int it = 0; it < 8; ++it) {
            long long fb = f4base + (long long)it * STRIDE;  // multiple of 64
            float4 v = g4[fb + lane];
            u64 m0 = __ballot(v.x != 0.0f);
            u64 m1 = __ballot(v.y != 0.0f);
            u64 m2 = __ballot(v.z != 0.0f);
            u64 m3 = __ballot(v.w != 0.0f);
            if (lane < 8) {
                u32 b0 = (u32)(m0 >> (8 * lane)) & 0xFFu;
                u32 b1 = (u32)(m1 >> (8 * lane)) & 0xFFu;
                u32 b2 = (u32)(m2 >> (8 * lane)) & 0xFFu;
                u32 b3 = (u32)(m3 >> (8 * lane)) & 0xFFu;
                u32 word = spread4(b0) | (spread4(b1) << 1) |
                           (spread4(b2) << 2) | (spread4(b3) << 3);
                A_bits[fb / 8 + lane] = word;
            }
        }
    } else {
        // ---- scores ----
        if (tid < DD) w[tid] = W[tid];
        __syncthreads();
        int i = (blockIdx.x - NBITBLK) * 256 + tid;
        const float4* hr = (const float4*)(h + i * DD);
        double x = 0.0;
        #pragma unroll
        for (int q = 0; q < DD / 4; ++q) {
            float4 v = hr[q];
            x += (double)v.x * (double)w[4 * q];
            x += (double)v.y * (double)w[4 * q + 1];
            x += (double)v.z * (double)w[4 * q + 2];
            x += (double)v.w * (double)w[4 * q + 3];
        }
        x += (double)b[0];
        double s = 1.0 / (1.0 + exp(-x));
        scores[i] = (float)s;
    }
}

// ---------------------------------------------------------------------------
// K2: exact stable top-k via rank-sort. rank(i) = #{j : v_j > v_i or
// (v_j == v_i and j < i)}  == position in (desc value, asc index) order.
// Also emits the float idx output.
// ---------------------------------------------------------------------------
__global__ void rank_kernel(const float* __restrict__ scores,
                            int* __restrict__ idxs,
                            float* __restrict__ vals,
                            float* __restrict__ out_idx) {
    int i = blockIdx.x;
    int tid = threadIdx.x;
    float vi = scores[i];
    int cnt = 0;
    #pragma unroll 4
    for (int j = tid; j < NN; j += 256) {
        float vj = scores[j];
        cnt += (vj > vi || (vj == vi && j < i)) ? 1 : 0;
    }
    __shared__ int red[256];
    red[tid] = cnt;
    __syncthreads();
    for (int s = 128; s > 0; s >>= 1) {
        if (tid < s) red[tid] += red[tid + s];
        __syncthreads();
    }
    if (tid == 0) {
        int r = red[0];
        if (r < KK) {
            idxs[r] = i;
            vals[r] = vi;
            out_idx[r] = (float)i;
        }
    }
}

// ---------------------------------------------------------------------------
// K3: new_h[r,:] = h[idx[r],:] * vals[r]   (float4 path)
// ---------------------------------------------------------------------------
__global__ void newh_kernel(const float* __restrict__ h,
                            const int* __restrict__ idxs,
                            const float* __restrict__ vals,
                            float* __restrict__ out_newh) {
    int t = blockIdx.x * 256 + threadIdx.x;   // over KK*DD/4
    int r = t >> 5;                           // DD/4 = 32 float4 per row
    int q = t & 31;
    float s = vals[r];
    float4 v = ((const float4*)(h + idxs[r] * DD))[q];
    float4 o = make_float4(v.x * s, v.y * s, v.z * s, v.w * s);
    ((float4*)out_newh)[t] = o;
}

// ---------------------------------------------------------------------------
// K5: for each selected row r: 2-hop row = OR over neighbors l of idx[r] of
// A_bits[l,:] (u64 loads, 1KB coalesced rows), then gather selected columns
// (idx) -> B_perm bits + degree popcount -> rdeg[r].
// ---------------------------------------------------------------------------
__global__ void union_kernel(const u32* __restrict__ A_bits,
                             const int* __restrict__ idxs,
                             u32* __restrict__ B_perm,
                             float* __restrict__ rdeg) {
    __shared__ u32 srow[NW];     // adjacency row of node idx[r]
    __shared__ u64 sOR64[NW / 2];// OR-accumulated 2-hop row
    __shared__ int nbrs[MAXNBR];
    __shared__ int ncnt;
    __shared__ int red[128];
    int r = blockIdx.x;
    int tid = threadIdx.x;              // 128 threads = 2 waves
    if (tid == 0) ncnt = 0;
    __syncthreads();
    int node = idxs[r];
    for (int t = tid; t < NW; t += 128) srow[t] = A_bits[node * NW + t];
    __syncthreads();
    // extract neighbor list of idx[r]
    for (int t = tid; t < NW; t += 128) {
        u32 word = srow[t];
        while (word) {
            int bpos = __ffs(word) - 1;
            word &= word - 1;
            int pos = atomicAdd(&ncnt, 1);
            if (pos < MAXNBR) nbrs[pos] = t * 32 + bpos;
        }
    }
    __syncthreads();
    int n = ncnt < MAXNBR ? ncnt : MAXNBR;
    u64 acc = 0ull;                     // thread owns u64 word tid of 128
    for (int q = 0; q < n; ++q) {
        const u64* row64 = (const u64*)(A_bits + (long long)nbrs[q] * NW);
        acc |= row64[tid];
    }
    sOR64[tid] = acc;
    __syncthreads();
    const u32* sOR = (const u32*)sOR64;
    // gather selected columns: bit c of B_perm row r = sOR bit idx[c]
    int lane = tid & 63;
    int cnt = 0;
    u64* outB = (u64*)(B_perm + r * KW);
    for (int c = tid; c < KK; c += 128) {
        int id = idxs[c];               // L1-hot 16KB table, coalesced
        int bit = (sOR[id >> 5] >> (id & 31)) & 1;
        u64 m = __ballot(bit != 0);
        if (lane == 0) outB[c >> 6] = m;
        cnt += bit;
    }
    red[tid] = cnt;
    __syncthreads();
    for (int s = 64; s > 0; s >>= 1) {
        if (tid < s) red[tid] += red[tid + s];
        __syncthreads();
    }
    if (tid == 0) rdeg[r] = 1.0f / (float)red[0];   // IEEE divide matches ref
}

// ---------------------------------------------------------------------------
// K6: g_new[r,c] = B_perm[r] bit c ? rdeg[c] : 0   (column-normalize, float4)
// ---------------------------------------------------------------------------
__global__ void writeg_kernel(const u32* __restrict__ B_perm,
                              const float* __restrict__ rdeg,
                              float* __restrict__ g_new) {
    int r = blockIdx.y;
    int c4 = blockIdx.x * 256 + threadIdx.x;   // index of float4
    int c = c4 * 4;
    u32 word = B_perm[r * KW + (c >> 5)];
    float4 rv = ((const float4*)rdeg)[c4];
    int sh = c & 31;                           // multiple of 4, <= 28
    float4 o;
    o.x = ((word >> sh) & 1u) ? rv.x : 0.0f;
    o.y = ((word >> (sh + 1)) & 1u) ? rv.y : 0.0f;
    o.z = ((word >> (sh + 2)) & 1u) ? rv.z : 0.0f;
    o.w = ((word >> (sh + 3)) & 1u) ? rv.w : 0.0f;
    ((float4*)g_new)[(long long)r * (KK / 4) + c4] = o;
}

// ---------------------------------------------------------------------------
extern "C" void kernel_launch(void* const* d_in, const int* in_sizes, int n_in,
                              void* d_out, int out_size, void* d_ws, size_t ws_size,
                              hipStream_t stream) {
    const float* g = (const float*)d_in[0];   // [NN, NN]
    const float* h = (const float*)d_in[1];   // [NN, DD]
    const float* W = (const float*)d_in[2];   // [DD]
    const float* b = (const float*)d_in[3];   // [1]

    float* out = (float*)d_out;
    float* out_gnew = out;                          // KK*KK
    float* out_newh = out + (long long)KK * KK;     // KK*DD
    float* out_idx  = out_newh + KK * DD;           // KK

    // d_ws layout (~2.1 MB)
    char* ws = (char*)d_ws;
    float*        scores = (float*)(ws + 0);              // 32 KB
    int*          idxs   = (int*)(ws + 32768);            // 16 KB
    float*        vals   = (float*)(ws + 49152);          // 16 KB
    float*        rdeg   = (float*)(ws + 65536);          // 16 KB
    u32*          B_perm = (u32*)(ws + 98304);            // 2 MB (512B-aligned)

    // A_bits (8 MB) lives in the g_new output region; dead before writeg runs.
    u32* A_bits = (u32*)d_out;

    // K1: bitize (8192 blocks) + scores (32 blocks) fused
    bitize_scores_kernel<<<NBITBLK + NN / 256, 256, 0, stream>>>(
        (const float4*)g, A_bits, h, W, b, scores);

    // K2: stable top-k rank sort (+ float idx output)
    rank_kernel<<<NN, 256, 0, stream>>>(scores, idxs, vals, out_idx);

    // K3: new_h
    newh_kernel<<<KK * DD / 4 / 256, 256, 0, stream>>>(h, idxs, vals, out_newh);

    // K5: row unions -> permuted bits + reciprocal degrees
    union_kernel<<<KK, 128, 0, stream>>>(A_bits, idxs, B_perm, rdeg);

    // K6: expand to fp32 g_new (overwrites A_bits scratch; it is dead now)
    dim3 wg_grid(KK / 4 / 256, KK);
    writeg_kernel<<<wg_grid, 256, 0, stream>>>(B_perm, rdeg, out_gnew);
}

// Round 4
// 437.223 us; speedup vs baseline: 1.1620x; 1.0102x over previous
//
#include <hip/hip_runtime.h>
#include <hip/hip_bf16.h>
#include <math.h>

// Problem constants (from reference)
#define NN 8192      // num nodes
#define DD 128       // in_dim
#define KK 4096      // k = max(2, int(0.5*N))
#define NW 256       // NN/32 words per full-row bitset
#define KW 128       // KK/32 words per selected-row bitset
#define MAXNBR 768   // binomial(8192,0.01): mean 82, sd 9 -> huge margin
#define NBITBLK 8192 // bitize blocks: 8192 blk * 256 thr * 8 f4 = NN*NN/4 f4
#define NEWHBLK 1024 // newh blocks fused into union grid (128 thr each)

typedef unsigned int u32;
typedef unsigned long long u64;

// spread 8 bits of x to bit positions 0,4,8,...,28
__device__ __forceinline__ u32 spread4(u32 x) {
    x = (x | (x << 12)) & 0x000F000Fu;
    x = (x | (x << 6))  & 0x03030303u;
    x = (x | (x << 3))  & 0x11111111u;
    return x;
}

// ---------------------------------------------------------------------------
// K1 (fused): blocks [0, NBITBLK): binarize g into row bitsets with
// lane-contiguous float4 loads (1KB/wave-instr) + 4x ballot packing.
// Blocks [NBITBLK, NBITBLK+32): scores[i] = sigmoid(h[i,:]·W + b) in fp64.
// ---------------------------------------------------------------------------
__global__ void bitize_scores_kernel(const float4* __restrict__ g4,
                                     u32* __restrict__ A_bits,
                                     const float* __restrict__ h,
                                     const float* __restrict__ W,
                                     const float* __restrict__ b,
                                     float* __restrict__ scores) {
    __shared__ float w[DD];
    int tid = threadIdx.x;
    if (blockIdx.x < NBITBLK) {
        // ---- bitize ----
        int lane = tid & 63;
        long long f4base = (long long)blockIdx.x * 256 + (tid & ~63);
        const long long STRIDE = (long long)NBITBLK * 256;
        #pragma unroll
        for (int it = 0; it < 8; ++it) {
            long long fb = f4base + (long long)it * STRIDE;  // multiple of 64
            float4 v = g4[fb + lane];
            u64 m0 = __ballot(v.x != 0.0f);
            u64 m1 = __ballot(v.y != 0.0f);
            u64 m2 = __ballot(v.z != 0.0f);
            u64 m3 = __ballot(v.w != 0.0f);
            if (lane < 8) {
                u32 b0 = (u32)(m0 >> (8 * lane)) & 0xFFu;
                u32 b1 = (u32)(m1 >> (8 * lane)) & 0xFFu;
                u32 b2 = (u32)(m2 >> (8 * lane)) & 0xFFu;
                u32 b3 = (u32)(m3 >> (8 * lane)) & 0xFFu;
                u32 word = spread4(b0) | (spread4(b1) << 1) |
                           (spread4(b2) << 2) | (spread4(b3) << 3);
                A_bits[fb / 8 + lane] = word;
            }
        }
    } else {
        // ---- scores ----
        if (tid < DD) w[tid] = W[tid];
        __syncthreads();
        int i = (blockIdx.x - NBITBLK) * 256 + tid;
        const float4* hr = (const float4*)(h + i * DD);
        double x = 0.0;
        #pragma unroll
        for (int q = 0; q < DD / 4; ++q) {
            float4 v = hr[q];
            x += (double)v.x * (double)w[4 * q];
            x += (double)v.y * (double)w[4 * q + 1];
            x += (double)v.z * (double)w[4 * q + 2];
            x += (double)v.w * (double)w[4 * q + 3];
        }
        x += (double)b[0];
        double s = 1.0 / (1.0 + exp(-x));
        scores[i] = (float)s;
    }
}

// ---------------------------------------------------------------------------
// K2: exact stable top-k via rank-sort. rank(i) = #{j : v_j > v_i or
// (v_j == v_i and j < i)}  == position in (desc value, asc index) order.
// Wave64 shuffle reduction (one __syncthreads total). Emits float idx too.
// ---------------------------------------------------------------------------
__global__ void rank_kernel(const float* __restrict__ scores,
                            int* __restrict__ idxs,
                            float* __restrict__ vals,
                            float* __restrict__ out_idx) {
    int i = blockIdx.x;
    int tid = threadIdx.x;           // 256 threads = 4 waves
    float vi = scores[i];
    int cnt = 0;
    #pragma unroll 4
    for (int j = tid; j < NN; j += 256) {
        float vj = scores[j];
        cnt += (vj > vi || (vj == vi && j < i)) ? 1 : 0;
    }
    // wave64 reduce
    #pragma unroll
    for (int s = 32; s > 0; s >>= 1) cnt += __shfl_down(cnt, s, 64);
    __shared__ int part[4];
    if ((tid & 63) == 0) part[tid >> 6] = cnt;
    __syncthreads();
    if (tid == 0) {
        int r = part[0] + part[1] + part[2] + part[3];
        if (r < KK) {
            idxs[r] = i;
            vals[r] = vi;
            out_idx[r] = (float)i;
        }
    }
}

// ---------------------------------------------------------------------------
// K3 (fused): blocks [0, KK): union — 2-hop row of idx[r] = OR over
// neighbors l of A_bits[l,:] (u64 loads, 4-way MLP), gather selected columns
// -> B_perm bits + degree popcount -> rdeg[r].
// Blocks [KK, KK+NEWHBLK): new_h[r,:] = h[idx[r],:] * vals[r] (float4).
// ---------------------------------------------------------------------------
__global__ void union_newh_kernel(const u32* __restrict__ A_bits,
                                  const int* __restrict__ idxs,
                                  u32* __restrict__ B_perm,
                                  float* __restrict__ rdeg,
                                  const float* __restrict__ h,
                                  const float* __restrict__ vals,
                                  float* __restrict__ out_newh) {
    int tid = threadIdx.x;              // 128 threads = 2 waves
    if (blockIdx.x >= KK) {
        // ---- newh ----
        int t = (blockIdx.x - KK) * 128 + tid;   // over KK*DD/4
        int r = t >> 5;                          // 32 float4 per row
        int q = t & 31;
        float s = vals[r];
        float4 v = ((const float4*)(h + idxs[r] * DD))[q];
        ((float4*)out_newh)[t] = make_float4(v.x * s, v.y * s, v.z * s, v.w * s);
        return;
    }
    __shared__ u32 srow[NW];     // adjacency row of node idx[r]
    __shared__ u64 sOR64[NW / 2];// OR-accumulated 2-hop row
    __shared__ int nbrs[MAXNBR];
    __shared__ int ncnt;
    __shared__ int red[128];
    int r = blockIdx.x;
    if (tid == 0) ncnt = 0;
    __syncthreads();
    int node = idxs[r];
    for (int t = tid; t < NW; t += 128) srow[t] = A_bits[node * NW + t];
    __syncthreads();
    // extract neighbor list of idx[r]
    for (int t = tid; t < NW; t += 128) {
        u32 word = srow[t];
        while (word) {
            int bpos = __ffs(word) - 1;
            word &= word - 1;
            int pos = atomicAdd(&ncnt, 1);
            if (pos < MAXNBR) nbrs[pos] = t * 32 + bpos;
        }
    }
    __syncthreads();
    int n = ncnt < MAXNBR ? ncnt : MAXNBR;
    // 4-way unrolled OR for memory-level parallelism
    u64 a0 = 0ull, a1 = 0ull, a2 = 0ull, a3 = 0ull;
    int q = 0;
    for (; q + 3 < n; q += 4) {
        a0 |= ((const u64*)(A_bits + (long long)nbrs[q]     * NW))[tid];
        a1 |= ((const u64*)(A_bits + (long long)nbrs[q + 1] * NW))[tid];
        a2 |= ((const u64*)(A_bits + (long long)nbrs[q + 2] * NW))[tid];
        a3 |= ((const u64*)(A_bits + (long long)nbrs[q + 3] * NW))[tid];
    }
    for (; q < n; ++q)
        a0 |= ((const u64*)(A_bits + (long long)nbrs[q] * NW))[tid];
    u64 acc = (a0 | a1) | (a2 | a3);
    sOR64[tid] = acc;
    __syncthreads();
    const u32* sOR = (const u32*)sOR64;
    // gather selected columns: bit c of B_perm row r = sOR bit idx[c]
    int lane = tid & 63;
    int cnt = 0;
    u64* outB = (u64*)(B_perm + r * KW);
    for (int c = tid; c < KK; c += 128) {
        int id = idxs[c];               // L1-hot 16KB table, coalesced
        int bit = (sOR[id >> 5] >> (id & 31)) & 1;
        u64 m = __ballot(bit != 0);
        if (lane == 0) outB[c >> 6] = m;
        cnt += bit;
    }
    red[tid] = cnt;
    __syncthreads();
    for (int s = 64; s > 0; s >>= 1) {
        if (tid < s) red[tid] += red[tid + s];
        __syncthreads();
    }
    if (tid == 0) rdeg[r] = 1.0f / (float)red[0];   // IEEE divide matches ref
}

// ---------------------------------------------------------------------------
// K4: g_new[r,c] = B_perm[r] bit c ? rdeg[c] : 0   (column-normalize, float4)
// ---------------------------------------------------------------------------
__global__ void writeg_kernel(const u32* __restrict__ B_perm,
                              const float* __restrict__ rdeg,
                              float* __restrict__ g_new) {
    int r = blockIdx.y;
    int c4 = blockIdx.x * 256 + threadIdx.x;   // index of float4
    int c = c4 * 4;
    u32 word = B_perm[r * KW + (c >> 5)];
    float4 rv = ((const float4*)rdeg)[c4];
    int sh = c & 31;                           // multiple of 4, <= 28
    float4 o;
    o.x = ((word >> sh) & 1u) ? rv.x : 0.0f;
    o.y = ((word >> (sh + 1)) & 1u) ? rv.y : 0.0f;
    o.z = ((word >> (sh + 2)) & 1u) ? rv.z : 0.0f;
    o.w = ((word >> (sh + 3)) & 1u) ? rv.w : 0.0f;
    ((float4*)g_new)[(long long)r * (KK / 4) + c4] = o;
}

// ---------------------------------------------------------------------------
extern "C" void kernel_launch(void* const* d_in, const int* in_sizes, int n_in,
                              void* d_out, int out_size, void* d_ws, size_t ws_size,
                              hipStream_t stream) {
    const float* g = (const float*)d_in[0];   // [NN, NN]
    const float* h = (const float*)d_in[1];   // [NN, DD]
    const float* W = (const float*)d_in[2];   // [DD]
    const float* b = (const float*)d_in[3];   // [1]

    float* out = (float*)d_out;
    float* out_gnew = out;                          // KK*KK
    float* out_newh = out + (long long)KK * KK;     // KK*DD
    float* out_idx  = out_newh + KK * DD;           // KK

    // d_ws layout (~2.1 MB)
    char* ws = (char*)d_ws;
    float*        scores = (float*)(ws + 0);              // 32 KB
    int*          idxs   = (int*)(ws + 32768);            // 16 KB
    float*        vals   = (float*)(ws + 49152);          // 16 KB
    float*        rdeg   = (float*)(ws + 65536);          // 16 KB
    u32*          B_perm = (u32*)(ws + 98304);            // 2 MB (512B-aligned)

    // A_bits (8 MB) lives in the g_new output region; dead before writeg runs.
    u32* A_bits = (u32*)d_out;

    // K1: bitize (8192 blocks) + scores (32 blocks) fused
    bitize_scores_kernel<<<NBITBLK + NN / 256, 256, 0, stream>>>(
        (const float4*)g, A_bits, h, W, b, scores);

    // K2: stable top-k rank sort (+ float idx output)
    rank_kernel<<<NN, 256, 0, stream>>>(scores, idxs, vals, out_idx);

    // K3: union (4096 blocks) + newh (1024 blocks) fused
    union_newh_kernel<<<KK + NEWHBLK, 128, 0, stream>>>(
        A_bits, idxs, B_perm, rdeg, h, vals, out_newh);

    // K4: expand to fp32 g_new (overwrites A_bits scratch; it is dead now)
    dim3 wg_grid(KK / 4 / 256, KK);
    writeg_kernel<<<wg_grid, 256, 0, stream>>>(B_perm, rdeg, out_gnew);
}